// Round 3
// baseline (270.090 us; speedup 1.0000x reference)
//
#include <hip/hip_runtime.h>

// Problem: inputs (4096, 8192) f32.
// out[i][j] = max over s in {0,2048,4096,6144} of in[i][(j-s) mod 8192]
//           = max_k in[i][(j mod 2048) + 2048*k],  k=0..3
// => compute 2048-wide per-row max of the 4 column quarters, write it 4x.
// Memory floor: 128 MiB read + 128 MiB write => ~43 us at 6.3 TB/s.

#define ROWS 4096
#define L    8192
#define Q    2048          // L/4
#define QV   (Q / 4)       // 512 float4 per quarter-row

typedef float f32x4 __attribute__((ext_vector_type(4)));

__global__ __launch_bounds__(256) void dense_max_pool_kernel(
    const float* __restrict__ in, float* __restrict__ out) {
    // 2 reduced float4 per thread: ROWS * QV / 2 threads total (1M)
    unsigned idx = (blockIdx.x * blockDim.x + threadIdx.x) * 2;
    unsigned row = idx >> 9;          // / QV (512)
    unsigned q   = idx & (QV - 1);    // % QV  (even, q+1 < QV since QV=512)

    const f32x4* in4  = (const f32x4*)in;
    f32x4*       out4 = (f32x4*)out;

    size_t base = (size_t)row * (L / 4) + q;   // float4 index of row start + q

    #pragma unroll
    for (int u = 0; u < 2; ++u) {
        size_t p = base + u;
        f32x4 a = in4[p];
        f32x4 b = in4[p + QV];
        f32x4 c = in4[p + 2 * QV];
        f32x4 d = in4[p + 3 * QV];

        f32x4 m;
        m.x = fmaxf(fmaxf(a.x, b.x), fmaxf(c.x, d.x));
        m.y = fmaxf(fmaxf(a.y, b.y), fmaxf(c.y, d.y));
        m.z = fmaxf(fmaxf(a.z, b.z), fmaxf(c.z, d.z));
        m.w = fmaxf(fmaxf(a.w, b.w), fmaxf(c.w, d.w));

        __builtin_nontemporal_store(m, &out4[p]);
        __builtin_nontemporal_store(m, &out4[p + QV]);
        __builtin_nontemporal_store(m, &out4[p + 2 * QV]);
        __builtin_nontemporal_store(m, &out4[p + 3 * QV]);
    }
}

extern "C" void kernel_launch(void* const* d_in, const int* in_sizes, int n_in,
                              void* d_out, int out_size, void* d_ws, size_t ws_size,
                              hipStream_t stream) {
    const float* in = (const float*)d_in[0];
    float* out = (float*)d_out;

    const int total_threads = ROWS * QV / 2;     // 1,048,576
    const int block = 256;
    const int grid = total_threads / block;      // 4096

    dense_max_pool_kernel<<<grid, block, 0, stream>>>(in, out);
}

// Round 4
// 227.852 us; speedup vs baseline: 1.1854x; 1.1854x over previous
//
#include <hip/hip_runtime.h>

// Problem: inputs (4096, 8192) f32.
// out[i][j] = max over s in {0,2048,4096,6144} of in[i][(j-s) mod 8192]
//           = max_k in[i][(j mod 2048) + 2048*k],  k=0..3
// => compute 2048-wide per-row max of the 4 column quarters, write it 4x.
// Compulsory traffic: 128 MiB read (partially L3-hot from harness restore)
// + 128 MiB write. Write floor at ~6.5 TB/s ≈ 21 us; total floor ~30-43 us.
//
// Round-3 lesson: nontemporal + stride-2 lane layout caused 1.75x HBM write
// amplification (WRITE_SIZE 235 MB vs 134 MB ideal). Revert to perfectly
// coalesced 1-float4/thread + normal (write-back, L2-merged) stores.

#define ROWS 4096u
#define L    8192u
#define Q    2048u         // L/4
#define QV   (Q / 4u)      // 512 float4 per quarter-row

__global__ __launch_bounds__(256) void dense_max_pool_kernel(
    const float* __restrict__ in, float* __restrict__ out) {
    // one thread per float4 of the reduced vector: ROWS * QV threads (2M)
    unsigned idx = blockIdx.x * blockDim.x + threadIdx.x;
    unsigned row = idx >> 9;          // / QV (512)
    unsigned q   = idx & (QV - 1u);   // % QV

    const float4* in4  = (const float4*)in;
    float4*       out4 = (float4*)out;

    unsigned base = row * (L / 4u) + q;   // float4 index; max < 2^23, fits u32

    float4 a = in4[base];
    float4 b = in4[base + QV];
    float4 c = in4[base + 2u * QV];
    float4 d = in4[base + 3u * QV];

    float4 m;
    m.x = fmaxf(fmaxf(a.x, b.x), fmaxf(c.x, d.x));
    m.y = fmaxf(fmaxf(a.y, b.y), fmaxf(c.y, d.y));
    m.z = fmaxf(fmaxf(a.z, b.z), fmaxf(c.z, d.z));
    m.w = fmaxf(fmaxf(a.w, b.w), fmaxf(c.w, d.w));

    out4[base]           = m;
    out4[base + QV]      = m;
    out4[base + 2u * QV] = m;
    out4[base + 3u * QV] = m;
}

extern "C" void kernel_launch(void* const* d_in, const int* in_sizes, int n_in,
                              void* d_out, int out_size, void* d_ws, size_t ws_size,
                              hipStream_t stream) {
    const float* in = (const float*)d_in[0];
    float* out = (float*)d_out;

    const unsigned total_threads = ROWS * QV;    // 2,097,152
    const unsigned block = 256;
    const unsigned grid = total_threads / block; // 8192

    dense_max_pool_kernel<<<grid, block, 0, stream>>>(in, out);
}